// Round 9
// baseline (174.092 us; speedup 1.0000x reference)
//
#include <hip/hip_runtime.h>
#include <hip/hip_bf16.h>

// SegmentLinear: y = sum_c (sx_c*sw_c) * (qx_c @ qw_c^T), int8-exact path.
// N = K = O = 4096, CHUNKS = 4, cs = 1024.

constexpr int NDIM = 4096;
constexpr int TOTAL4 = (NDIM * NDIM) / 4;   // float4 count per matrix

typedef int i32x4 __attribute__((ext_vector_type(4)));

// ---------------------------------------------------------------- amax pass
__global__ __launch_bounds__(256) void amax_kernel(
    const float* __restrict__ x, const float* __restrict__ w,
    unsigned int* __restrict__ amax) {
  const int t = threadIdx.x;
  const int c = blockIdx.x & 3;  // grid stride (1024*256 float4) is a multiple
                                 // of K/4=1024 -> whole block stays in chunk c
  float mx = 0.f, mw = 0.f;
  const float4* x4 = (const float4*)x;
  const float4* w4 = (const float4*)w;
  const int stride = 1024 * 256;
  for (int i = blockIdx.x * 256 + t; i < TOTAL4; i += stride) {
    float4 v = x4[i];
    mx = fmaxf(mx, fmaxf(fmaxf(fabsf(v.x), fabsf(v.y)),
                         fmaxf(fabsf(v.z), fabsf(v.w))));
    float4 u = w4[i];
    mw = fmaxf(mw, fmaxf(fmaxf(fabsf(u.x), fabsf(u.y)),
                         fmaxf(fabsf(u.z), fabsf(u.w))));
  }
  __shared__ float r0[256], r1[256];
  r0[t] = mx; r1[t] = mw;
  __syncthreads();
  for (int off = 128; off; off >>= 1) {
    if (t < off) {
      r0[t] = fmaxf(r0[t], r0[t + off]);
      r1[t] = fmaxf(r1[t], r1[t + off]);
    }
    __syncthreads();
  }
  if (t == 0) {
    atomicMax(&amax[c],     __float_as_uint(r0[0]));  // non-neg: uint order == float order
    atomicMax(&amax[4 + c], __float_as_uint(r1[0]));
  }
}

// ------------------------------------------------------------- quantize pass
__device__ __forceinline__ signed char quant1(float v, float s) {
  float r = rintf(v / s);                       // round-half-even, IEEE div: matches numpy
  r = fminf(fmaxf(r, -127.f), 127.f);
  return (signed char)(int)r;
}

__global__ __launch_bounds__(256) void quant_kernel(
    const float* __restrict__ x, const float* __restrict__ w,
    const unsigned int* __restrict__ amax,
    signed char* __restrict__ qx, signed char* __restrict__ qw) {
  const int t = threadIdx.x;
  const int c = blockIdx.x & 3;
  const float sx = fmaxf(__uint_as_float(amax[c])     / 127.0f, 1e-8f);
  const float sw = fmaxf(__uint_as_float(amax[4 + c]) / 127.0f, 1e-8f);
  const float4* x4 = (const float4*)x;
  const float4* w4 = (const float4*)w;
  char4* qx4 = (char4*)qx;
  char4* qw4 = (char4*)qw;
  const int stride = 1024 * 256;
  for (int i = blockIdx.x * 256 + t; i < TOTAL4; i += stride) {
    float4 v = x4[i];
    char4 q;
    q.x = quant1(v.x, sx); q.y = quant1(v.y, sx);
    q.z = quant1(v.z, sx); q.w = quant1(v.w, sx);
    qx4[i] = q;
    float4 u = w4[i];
    char4 p;
    p.x = quant1(u.x, sw); p.y = quant1(u.y, sw);
    p.z = quant1(u.z, sw); p.w = quant1(u.w, sw);
    qw4[i] = p;
  }
}

// ------------------------------------------------------------------ i8 GEMM
__device__ __forceinline__ void async16(const void* g, void* l) {
  __builtin_amdgcn_global_load_lds(
      (const __attribute__((address_space(1))) void*)g,
      (__attribute__((address_space(3))) void*)l, 16, 0, 0);
}

// m201-style 8-phase port for i8. BM=256, BN=128, 512 threads = 8 waves
// (4x2), per-wave 64x64 out (iacc 64 + facc 64 regs, the proven shape).
// K processed in 64-byte HALVES via 4 rotating half-buffers
// (A 256x64B = 16 KB, B 128x64B = 8 KB per half; 96 KB LDS, 1 block/CU).
// Per half h (buf = h&3), 2 phases:
//   phA: ds_read av[0..3]+bv[0,1] (6) | stage A-part of half h+2 (2 loads)
//        BAR; lgkmcnt(0); setprio1; 8 MFMA (m0..3 x n0,1); setprio0; BAR
//   phB: ds_read bv[2,3] (2)         | stage B-part of half h+2 (1 load)
//        BAR; lgkmcnt(0); setprio1; 8 MFMA (m0..3 x n2,3); setprio0;
//        vmcnt(3)  <- COUNTED: retires half h+1's 3 loads (h+2's 3 stay in
//                     flight across the barrier; never drains to 0 mid-loop)
//        BAR
// Ledger: stage of h+2 writes buf (h+2)&3 = (h-2)&3, whose readers all
// passed the end-of-(h-2) barrier before this issue point -> race-free.
// h+1's loads get a full half (~2 MFMA phases) of latency cover.
// Swizzle (R3-proven for 64B rows): 16B slot' = slot ^ ((row>>1)&3); max
// 2-way bank aliasing (free). Same involution pre-applied to global sources
// (linear global_load_lds dests).
__global__ __launch_bounds__(512, 1) void gemm_i8_kernel(
    const signed char* __restrict__ qx, const signed char* __restrict__ qw,
    const unsigned int* __restrict__ amax, float* __restrict__ out) {
  __shared__ __align__(1024) signed char lds_a[4][16384];
  __shared__ __align__(1024) signed char lds_b[4][8192];

  const int t = threadIdx.x;          // 0..511
  const int lane = t & 63;
  const int wave = t >> 6;            // 0..7
  const int brow = blockIdx.y * 256;
  const int bcol = blockIdx.x * 128;
  const int wr = wave >> 1;           // 0..3  (m-dim, 64 rows each)
  const int wc = wave & 1;            // 0..1  (n-dim, 64 cols each)

  // per-chunk combined scales -- computed and drained before any STAGE.
  const float s0 = fmaxf(__uint_as_float(amax[0]) / 127.0f, 1e-8f) *
                   fmaxf(__uint_as_float(amax[4]) / 127.0f, 1e-8f);
  const float s1 = fmaxf(__uint_as_float(amax[1]) / 127.0f, 1e-8f) *
                   fmaxf(__uint_as_float(amax[5]) / 127.0f, 1e-8f);
  const float s2 = fmaxf(__uint_as_float(amax[2]) / 127.0f, 1e-8f) *
                   fmaxf(__uint_as_float(amax[6]) / 127.0f, 1e-8f);
  const float s3 = fmaxf(__uint_as_float(amax[3]) / 127.0f, 1e-8f) *
                   fmaxf(__uint_as_float(amax[7]) / 127.0f, 1e-8f);
  asm volatile("s_waitcnt vmcnt(0)" ::: "memory");
  __builtin_amdgcn_sched_barrier(0);

  // staging: A j-load (j=0,1) of thread t -> LDS byte j*8192 + t*16
  //   -> LDS row = j*128 + (t>>2), slot = t&3. B: row = t>>2, slot = t&3.
  // Global col16 pre-swizzled: (t&3) ^ ((row>>1)&3) = (t&3) ^ ((t>>3)&3)
  // (identical for j=0,1 since j*64 == 0 mod 4).
  const int sr = t >> 2;
  const int scol = (((t & 3) ^ ((t >> 3) & 3)) << 4);
  const signed char* gA = qx + (size_t)(brow + sr) * NDIM + scol;
  const signed char* gB = qw + (size_t)(bcol + sr) * NDIM + scol;

  // fragment reads: row = w*64 + m*16 + (lane&15); (row>>1)&3 = ((lane&15)>>1)&3
  const int kg = lane >> 4;
  const int l15 = lane & 15;
  const int ksl = ((kg ^ ((l15 >> 1) & 3)) << 4);
  const int offa = (wr * 64 + l15) * 64 + ksl;   // + m*1024 + buf*16384
  const int offb = (wc * 64 + l15) * 64 + ksl;   // + n*1024 + buf*8192

#define STAGE_A(BUF, H)                                                  \
  do {                                                                   \
    const size_t kb_ = (size_t)(H) * 64;                                 \
    async16(gA + kb_,                &lds_a[BUF][0] + t * 16);           \
    async16(gA + kb_ + 128u * NDIM,  &lds_a[BUF][8192] + t * 16);        \
  } while (0)
#define STAGE_B(BUF, H)                                                  \
  do {                                                                   \
    const size_t kb_ = (size_t)(H) * 64;                                 \
    async16(gB + kb_, &lds_b[BUF][0] + t * 16);                          \
  } while (0)

#define LDA(BUF, M) (*(const i32x4*)&lds_a[BUF][offa + (M) * 1024])
#define LDB(BUF, N) (*(const i32x4*)&lds_b[BUF][offb + (N) * 1024])
#define MM(AV, BV, M, N) \
  iacc[M][N] = __builtin_amdgcn_mfma_i32_16x16x64_i8((AV), (BV), iacc[M][N], 0, 0, 0)

#define WAITL \
  asm volatile("s_waitcnt lgkmcnt(0)" ::: "memory"); \
  __builtin_amdgcn_sched_barrier(0)
#define BAR \
  __builtin_amdgcn_s_barrier(); \
  __builtin_amdgcn_sched_barrier(0)

  // prologue: halves 0 and 1 fully staged (oldest-first for FIFO vmcnt)
  STAGE_A(0, 0); STAGE_B(0, 0);
  STAGE_A(1, 1); STAGE_B(1, 1);

  i32x4 iacc[4][4];
  float facc[4][4][4];
#pragma unroll
  for (int m = 0; m < 4; ++m)
#pragma unroll
    for (int n = 0; n < 4; ++n) {
      iacc[m][n] = i32x4{0, 0, 0, 0};
#pragma unroll
      for (int j = 0; j < 4; ++j) facc[m][n][j] = 0.f;
    }

  asm volatile("s_waitcnt vmcnt(3)" ::: "memory");   // half 0 resident
  __builtin_amdgcn_sched_barrier(0);
  BAR;

#define FOLD(S)                                                         \
  do {                                                                  \
    _Pragma("unroll")                                                   \
    for (int m = 0; m < 4; ++m)                                         \
      _Pragma("unroll")                                                 \
      for (int n = 0; n < 4; ++n) {                                     \
        _Pragma("unroll")                                               \
        for (int j = 0; j < 4; ++j) facc[m][n][j] += (S) * (float)iacc[m][n][j]; \
        iacc[m][n] = i32x4{0, 0, 0, 0};                                 \
      }                                                                 \
  } while (0)

  // HALF: EN = stage half H2 (compile-time), VM = end-of-half waitcnt instr
#define HALF(BUF, H2, EN, VM)                                           \
  do {                                                                  \
    i32x4 av0 = LDA(BUF, 0), av1 = LDA(BUF, 1);                         \
    i32x4 av2 = LDA(BUF, 2), av3 = LDA(BUF, 3);                         \
    i32x4 bv0 = LDB(BUF, 0), bv1 = LDB(BUF, 1);                         \
    if (EN) STAGE_A(((BUF) + 2) & 3, H2);                               \
    BAR;                                                                \
    WAITL;                                                              \
    __builtin_amdgcn_s_setprio(1);                                      \
    MM(av0, bv0, 0, 0); MM(av1, bv0, 1, 0);                             \
    MM(av2, bv0, 2, 0); MM(av3, bv0, 3, 0);                             \
    MM(av0, bv1, 0, 1); MM(av1, bv1, 1, 1);                             \
    MM(av2, bv1, 2, 1); MM(av3, bv1, 3, 1);                             \
    __builtin_amdgcn_s_setprio(0);                                      \
    BAR;                                                                \
    i32x4 bv2 = LDB(BUF, 2), bv3 = LDB(BUF, 3);                         \
    if (EN) STAGE_B(((BUF) + 2) & 3, H2);                               \
    BAR;                                                                \
    WAITL;                                                              \
    __builtin_amdgcn_s_setprio(1);                                      \
    MM(av0, bv2, 0, 2); MM(av1, bv2, 1, 2);                             \
    MM(av2, bv2, 2, 2); MM(av3, bv2, 3, 2);                             \
    MM(av0, bv3, 0, 3); MM(av1, bv3, 1, 3);                             \
    MM(av2, bv3, 2, 3); MM(av3, bv3, 3, 3);                             \
    __builtin_amdgcn_s_setprio(0);                                      \
    asm volatile(VM ::: "memory");                                      \
    __builtin_amdgcn_sched_barrier(0);                                  \
    BAR;                                                                \
  } while (0)

  // 64 halves (32 K-tiles of 128B); chunk c = halves 16c .. 16c+15.
#pragma unroll 1
  for (int hh = 0; hh < 15; ++hh) {   // halves 0..59
    const int h = hh * 4;
    HALF(0, h + 2, 1, "s_waitcnt vmcnt(3)");
    HALF(1, h + 3, 1, "s_waitcnt vmcnt(3)");
    HALF(2, h + 4, 1, "s_waitcnt vmcnt(3)");
    HALF(3, h + 5, 1, "s_waitcnt vmcnt(3)");
    if ((hh & 3) == 3) {              // after halves 15,31,47 -> chunks 0,1,2
      const int ci = hh >> 2;
      FOLD(ci == 0 ? s0 : ci == 1 ? s1 : s2);
    }
  }
  HALF(0, 62, 1, "s_waitcnt vmcnt(3)");   // h=60, stage 62
  HALF(1, 63, 1, "s_waitcnt vmcnt(3)");   // h=61, stage 63
  HALF(2, 0, 0, "s_waitcnt vmcnt(0)");    // h=62, drain -> 63 resident
  HALF(3, 0, 0, "s_nop 0");               // h=63
  FOLD(s3);

  // C/D layout (16x16): col = lane&15, row = (lane>>4)*4 + j
  const int orow = brow + wr * 64 + (lane >> 4) * 4;
  const int ocol = bcol + wc * 64 + l15;
#pragma unroll
  for (int m = 0; m < 4; ++m)
#pragma unroll
    for (int n = 0; n < 4; ++n)
#pragma unroll
      for (int j = 0; j < 4; ++j)
        out[(size_t)(orow + m * 16 + j) * NDIM + (ocol + n * 16)] = facc[m][n][j];
#undef STAGE_A
#undef STAGE_B
#undef LDA
#undef LDB
#undef MM
#undef WAITL
#undef BAR
#undef FOLD
#undef HALF
}

// ---------------------------------------------------------------- launcher
extern "C" void kernel_launch(void* const* d_in, const int* in_sizes, int n_in,
                              void* d_out, int out_size, void* d_ws, size_t ws_size,
                              hipStream_t stream) {
  const float* x = (const float*)d_in[0];
  const float* w = (const float*)d_in[1];
  float* out = (float*)d_out;

  unsigned int* amax = (unsigned int*)d_ws;                 // 8 uints
  signed char* qx = (signed char*)d_ws + 256;               // 16 MiB
  signed char* qw = qx + (size_t)NDIM * NDIM;               // 16 MiB

  hipMemsetAsync(d_ws, 0, 256, stream);
  amax_kernel<<<1024, 256, 0, stream>>>(x, w, amax);
  quant_kernel<<<1024, 256, 0, stream>>>(x, w, amax, qx, qw);
  dim3 grid(NDIM / 128, NDIM / 256);   // x: 32 col-tiles(128), y: 16 row-tiles(256)
  gemm_i8_kernel<<<grid, 512, 0, stream>>>(qx, qw, amax, out);
}